// Round 2
// baseline (307.960 us; speedup 1.0000x reference)
//
#include <hip/hip_runtime.h>

// TCM_77464030151162: x(N,128)@w1+b1 -> split 64/64 -> two gathered 3^3 sparse
// convs (27 offsets, 64x64 each, ReLU) -> +2*conv_x residual -> concat@w2+b2 -> +x.
// fp32 wire, bf16 MFMA compute.
// R6: conv rewritten barrier-free. R5 post-mortem: per-k __syncthreads (vmcnt(0)
// drain of random gathers) + per-wave 8KB/k LDS B-reads were the cost; more waves
// made it worse (doubled LDS+stage traffic). Now: 1-wave blocks, 64 rows/wave,
// NO LDS, NO barriers; B-fragments read directly from L1/L2-resident weights;
// register rings: idx dist 5 (ring 6), A-gather dist 1, B dist 1, unroll 6
// (all ring indices compile-time). GEMMs unchanged (isolate the conv change).

#define N_PTS 100000
#define NBLK64 1563 // ceil(100000/64)

typedef __attribute__((ext_vector_type(8))) short frag_ab; // 8 bf16 (4 VGPRs)
typedef __attribute__((ext_vector_type(4))) float f32x4;   // MFMA 16x16 C/D
#define ZFRAG frag_ab{0, 0, 0, 0, 0, 0, 0, 0}

__device__ __forceinline__ unsigned short f2bf(float f) {
  union { float f; unsigned int i; } v; v.f = f;
  unsigned int r = v.i + 0x7fffu + ((v.i >> 16) & 1u); // RNE
  return (unsigned short)(r >> 16);
}
__device__ __forceinline__ float bf2f(unsigned short u) {
  union { unsigned int i; float f; } v; v.i = ((unsigned int)u) << 16; return v.f;
}

// async global->LDS, 16B per lane. LDS dest = wave-uniform base + lane*16 (m104).
__device__ __forceinline__ void gload_lds16(const unsigned short* g, unsigned short* l) {
  __builtin_amdgcn_global_load_lds(
      (const __attribute__((address_space(1))) unsigned int*)g,
      (__attribute__((address_space(3))) unsigned int*)(unsigned int)(size_t)l,
      16, 0, 0);
}

// ---- weight convert+transpose ----
// w1T/w2T (for LDS-staged GEMMs): logical (d,c); 16B chunk (c>>3) stored at
// chunk^(d&15). rw1T/rw2T (read direct from global by conv): plain transposed
// d-major, rwT[k][d][c] = bf16(rw[k][c][d]) -- no swizzle (no LDS banks involved).
__global__ __launch_bounds__(256) void k_prep(
    const float* __restrict__ w1, const float* __restrict__ w2,
    const float* __restrict__ rw1, const float* __restrict__ rw2,
    unsigned short* __restrict__ w1T, unsigned short* __restrict__ w2T,
    unsigned short* __restrict__ rw1T, unsigned short* __restrict__ rw2T) {
  int t = blockIdx.x * 256 + threadIdx.x;
  if (t < 128 * 128) {
    int c = t >> 7, d = t & 127;
    int pos = d * 128 + ((((c >> 3) ^ (d & 15)) << 3) | (c & 7));
    w1T[pos] = f2bf(w1[t]);
    w2T[pos] = f2bf(w2[t]);
  }
  if (t < 27 * 64 * 64) {
    int k = t >> 12, r = t & 4095, c = r >> 6, d = r & 63;
    int pos = (k << 12) + d * 64 + c;
    rw1T[pos] = f2bf(rw1[t]);
    rw2T[pos] = f2bf(rw2[t]);
  }
}

// ---- y = bf16(x) @ w1 + b1 ; w1T staged in LDS once; 16 rows/wave ----
__global__ __launch_bounds__(256) void k_gemm_in(
    const float* __restrict__ x, const unsigned short* __restrict__ w1T,
    const float* __restrict__ b1, unsigned short* __restrict__ y) {
  __shared__ unsigned short sw[16384]; // 32KB
  const int tid = threadIdx.x, lane = tid & 63, w = tid >> 6;
  const int m16 = lane & 15, q = lane >> 4;
#pragma unroll
  for (int r = 0; r < 8; ++r) {
    const int off = (w * 8 + r) * 512 + lane * 8;
    gload_lds16(w1T + off, &sw[off]);
  }
  __syncthreads();
  const int rowbase = blockIdx.x * 64 + w * 16;
  const int r0 = rowbase + m16;
  const int rc = r0 < N_PTS ? r0 : N_PTS - 1;
  f32x4 acc[8] = {};
#pragma unroll
  for (int kk = 0; kk < 4; ++kk) {
    const float* xp = x + (size_t)rc * 128 + kk * 32 + q * 8;
    float4 f0 = *(const float4*)xp;
    float4 f1 = *(const float4*)(xp + 4);
    frag_ab a;
    a[0] = (short)f2bf(f0.x); a[1] = (short)f2bf(f0.y);
    a[2] = (short)f2bf(f0.z); a[3] = (short)f2bf(f0.w);
    a[4] = (short)f2bf(f1.x); a[5] = (short)f2bf(f1.y);
    a[6] = (short)f2bf(f1.z); a[7] = (short)f2bf(f1.w);
#pragma unroll
    for (int ct = 0; ct < 8; ++ct) {
      const int d = ct * 16 + m16;
      const int phys = ((kk << 2) | q) ^ m16;
      frag_ab bf = *(const frag_ab*)(&sw[d * 128 + phys * 8]);
      acc[ct] = __builtin_amdgcn_mfma_f32_16x16x32_bf16(a, bf, acc[ct], 0, 0, 0);
    }
  }
#pragma unroll
  for (int ct = 0; ct < 8; ++ct) {
    const int col = ct * 16 + m16;
    const float bias = b1[col];
#pragma unroll
    for (int j = 0; j < 4; ++j) {
      int r = rowbase + q * 4 + j;
      if (r < N_PTS) y[(size_t)r * 128 + col] = f2bf(acc[ct][j] + bias);
    }
  }
}

// ---- gathered sparse conv: 1-wave blocks, 64 rows/wave, no LDS, no barriers ----
// B-fragments read directly from global (weights are L1/L2 resident).
__device__ __forceinline__ void conv_loadI(int I[4], const int* nbr, int kc,
                                           const int p[4], const bool v[4]) {
#pragma unroll
  for (int rt = 0; rt < 4; ++rt)
    I[rt] = v[rt] ? nbr[(size_t)kc * N_PTS + p[rt]] : -1;
}

__device__ __forceinline__ void conv_loadB(frag_ab B[4][2],
                                           const unsigned short* wk,
                                           int m16, int q) {
#pragma unroll
  for (int ct = 0; ct < 4; ++ct)
#pragma unroll
    for (int kk = 0; kk < 2; ++kk)
      B[ct][kk] = *(const frag_ab*)(wk + (ct * 16 + m16) * 64 + kk * 32 + q * 8);
}

__device__ __forceinline__ void conv_gatherA(frag_ab A[4][2], const int I[4],
                                             const unsigned short* feat,
                                             int fstride, int q) {
#pragma unroll
  for (int rt = 0; rt < 4; ++rt) {
    A[rt][0] = ZFRAG; A[rt][1] = ZFRAG;
    if (I[rt] >= 0) {
      const unsigned short* fp = feat + (size_t)I[rt] * fstride + q * 8;
      A[rt][0] = *(const frag_ab*)fp;
      A[rt][1] = *(const frag_ab*)(fp + 32);
    }
  }
}

__device__ __forceinline__ void conv_mfma(f32x4 acc[4][4], const frag_ab A[4][2],
                                          const frag_ab B[4][2]) {
#pragma unroll
  for (int kk = 0; kk < 2; ++kk)
#pragma unroll
    for (int rt = 0; rt < 4; ++rt)
#pragma unroll
      for (int ct = 0; ct < 4; ++ct)
        acc[rt][ct] =
            __builtin_amdgcn_mfma_f32_16x16x32_bf16(A[rt][kk], B[ct][kk], acc[rt][ct], 0, 0, 0);
}

template <bool FUSE>
__global__ __launch_bounds__(64, 2) void k_conv(
    const unsigned short* __restrict__ feat, const int fstride,
    const int* __restrict__ nbr,
    const unsigned short* __restrict__ rwT, const float* __restrict__ rb,
    const unsigned short* __restrict__ res, unsigned short* __restrict__ out) {
  const int lane = threadIdx.x & 63;
  const int m16 = lane & 15, q = lane >> 4;
  const int rowbase = blockIdx.x * 64;

  int p[4]; bool v[4];
#pragma unroll
  for (int rt = 0; rt < 4; ++rt) {
    p[rt] = rowbase + rt * 16 + m16;
    v[rt] = p[rt] < N_PTS;
  }

  int I[6][4];        // idx ring: idx[j] lives in slot j%6, loaded at iter j-5
  frag_ab A[2][4][2]; // A ring: A[k] in slot k&1, gathered at iter k-1
  frag_ab B[2][4][2]; // B ring: B[k] in slot k&1, loaded at iter k-1
  f32x4 acc[4][4] = {};

  // prologue: fill idx slots 0..4, B[0], A[0]
  conv_loadI(I[0], nbr, 0, p, v);
  conv_loadI(I[1], nbr, 1, p, v);
  conv_loadI(I[2], nbr, 2, p, v);
  conv_loadI(I[3], nbr, 3, p, v);
  conv_loadI(I[4], nbr, 4, p, v);
  conv_loadB(B[0], rwT, m16, q);
  conv_gatherA(A[0], I[0], feat, fstride, q);

  // main loop k = 0..23 (unroll 6 so all ring indices are compile-time)
  for (int k0 = 0; k0 < 24; k0 += 6) {
#pragma unroll
    for (int u = 0; u < 6; ++u) {
      const int k = k0 + u;
      const int kc = (k + 5 < 27) ? k + 5 : 26; // clamp keeps nbr reads in-bounds
      conv_loadI(I[(u + 5) % 6], nbr, kc, p, v);
      conv_loadB(B[(u + 1) & 1], rwT + ((size_t)(k + 1) << 12), m16, q);
      conv_gatherA(A[(u + 1) & 1], I[(u + 1) % 6], feat, fstride, q);
      conv_mfma(acc, A[u & 1], B[u & 1]);
    }
  }
  // epilogue k = 24,25,26 (slots: 24%6==0 so parity matches main loop)
  conv_loadB(B[1], rwT + ((size_t)25 << 12), m16, q);
  conv_gatherA(A[1], I[25 % 6], feat, fstride, q);
  conv_mfma(acc, A[0], B[0]); // k=24
  conv_loadB(B[0], rwT + ((size_t)26 << 12), m16, q);
  conv_gatherA(A[0], I[26 % 6], feat, fstride, q);
  conv_mfma(acc, A[1], B[1]); // k=25
  conv_mfma(acc, A[0], B[0]); // k=26

#pragma unroll
  for (int ct = 0; ct < 4; ++ct) {
    const int col = ct * 16 + m16;
    const float bias = rb[col];
#pragma unroll
    for (int rt = 0; rt < 4; ++rt)
#pragma unroll
      for (int j = 0; j < 4; ++j) {
        const int r = rowbase + rt * 16 + q * 4 + j;
        if (r < N_PTS) {
          float vv = acc[rt][ct][j] + bias;
          vv = vv > 0.f ? vv : 0.f;
          if constexpr (FUSE) vv += 2.f * bf2f(res[(size_t)r * 128 + col]);
          out[(size_t)r * 64 + col] = f2bf(vv);
        }
      }
  }
}

// ---- out = x + [z1 | y[:,64:]] @ w2 + b2 ; w2T staged in LDS once; 16 rows/wave ----
__global__ __launch_bounds__(256) void k_gemm_out(
    const float* __restrict__ x, const unsigned short* __restrict__ z1,
    const unsigned short* __restrict__ y, const unsigned short* __restrict__ w2T,
    const float* __restrict__ b2, float* __restrict__ out) {
  __shared__ unsigned short sw[16384]; // 32KB
  const int tid = threadIdx.x, lane = tid & 63, w = tid >> 6;
  const int m16 = lane & 15, q = lane >> 4;
#pragma unroll
  for (int r = 0; r < 8; ++r) {
    const int off = (w * 8 + r) * 512 + lane * 8;
    gload_lds16(w2T + off, &sw[off]);
  }
  __syncthreads();
  const int rowbase = blockIdx.x * 64 + w * 16;
  const int r0 = rowbase + m16;
  const int rc = r0 < N_PTS ? r0 : N_PTS - 1;
  f32x4 acc[8] = {};
#pragma unroll
  for (int kk = 0; kk < 4; ++kk) {
    const unsigned short* ap = (kk < 2)
        ? (z1 + (size_t)rc * 64 + kk * 32 + q * 8)
        : (y + (size_t)rc * 128 + 64 + (kk - 2) * 32 + q * 8);
    frag_ab a = *(const frag_ab*)ap;
#pragma unroll
    for (int ct = 0; ct < 8; ++ct) {
      const int d = ct * 16 + m16;
      const int phys = ((kk << 2) | q) ^ m16;
      frag_ab bf = *(const frag_ab*)(&sw[d * 128 + phys * 8]);
      acc[ct] = __builtin_amdgcn_mfma_f32_16x16x32_bf16(a, bf, acc[ct], 0, 0, 0);
    }
  }
#pragma unroll
  for (int ct = 0; ct < 8; ++ct) {
    const int col = ct * 16 + m16;
    const float bias = b2[col];
#pragma unroll
    for (int j = 0; j < 4; ++j) {
      int r = rowbase + q * 4 + j;
      if (r < N_PTS) {
        size_t o = (size_t)r * 128 + col;
        out[o] = acc[ct][j] + bias + x[o];
      }
    }
  }
}

extern "C" void kernel_launch(void* const* d_in, const int* in_sizes, int n_in,
                              void* d_out, int out_size, void* d_ws, size_t ws_size,
                              hipStream_t stream) {
  const float* x   = (const float*)d_in[0];
  const float* w1  = (const float*)d_in[1];
  const float* b1  = (const float*)d_in[2];
  const float* w2  = (const float*)d_in[3];
  const float* b2  = (const float*)d_in[4];
  const float* rw1 = (const float*)d_in[5];
  const float* rb1 = (const float*)d_in[6];
  const float* rw2 = (const float*)d_in[7];
  const float* rb2 = (const float*)d_in[8];
  const int* nbr = (const int*)d_in[9];
  float* out = (float*)d_out;

  char* ws = (char*)d_ws;
  unsigned short* w1T  = (unsigned short*)(ws);                       // 32 KB
  unsigned short* w2T  = (unsigned short*)(ws + 32768);               // 32 KB
  unsigned short* rw1T = (unsigned short*)(ws + 65536);               // 216 KB
  unsigned short* rw2T = (unsigned short*)(ws + 286720);              // 216 KB
  unsigned short* y    = (unsigned short*)(ws + 507904);              // 25.6 MB
  unsigned short* r1   = (unsigned short*)(ws + 507904 + 25600000);   // 12.8 MB
  unsigned short* z1   = (unsigned short*)(ws + 507904 + 38400000);   // 12.8 MB

  k_prep<<<432, 256, 0, stream>>>(w1, w2, rw1, rw2, w1T, w2T, rw1T, rw2T);
  k_gemm_in<<<NBLK64, 256, 0, stream>>>(x, w1T, b1, y);
  k_conv<false><<<NBLK64, 64, 0, stream>>>(y, 128, nbr, rw1T, rb1, nullptr, r1);
  k_conv<true><<<NBLK64, 64, 0, stream>>>(r1, 64, nbr, rw2T, rb2, y, z1);
  k_gemm_out<<<NBLK64, 256, 0, stream>>>(x, z1, y, w2T, b2, out);
}

// Round 4
// 275.306 us; speedup vs baseline: 1.1186x; 1.1186x over previous
//
#include <hip/hip_runtime.h>

// TCM_77464030151162: x(N,128)@w1+b1 -> split 64/64 -> two gathered 3^3 sparse
// convs (27 offsets, 64x64 each, ReLU) -> +2*conv_x residual -> concat@w2+b2 -> +x.
// fp32 wire, bf16 MFMA compute.
// R8: R7's counted-vmcnt conv pipeline with airtight counts. R7 failed because
// tail-clamped duplicate nbr loads were CSE-able -> per-iter vmem count != 8 ->
// vmcnt(8) no longer retired the previous stage before the barrier (stale
// weights for one k-slice). Now: main loop k=0..23 only unique+valid loads
// (8/iter, vmcnt(8)); explicit epilogue k=24/25/26 with exact waits
// vmcnt(6)/(4)/(0); runtime outer k0+=4 loop + unrolled u=0..3 so all ring
// indices are compile-time (no scratch, rule #20); sched_barrier(0) after each
// waitcnt (rule #18). 128 rows/block, 4 waves, grid 782, 4-deep LDS weight ring,
// raw s_barrier (no vmcnt(0) drain in main loop). GEMMs unchanged.

#define N_PTS 100000
#define NBLK64 1563  // ceil(100000/64)
#define NBLK128 782  // ceil(100000/128)

typedef __attribute__((ext_vector_type(8))) short frag_ab; // 8 bf16 (4 VGPRs)
typedef __attribute__((ext_vector_type(4))) float f32x4;   // MFMA 16x16 C/D
#define ZFRAG frag_ab{0, 0, 0, 0, 0, 0, 0, 0}

__device__ __forceinline__ unsigned short f2bf(float f) {
  union { float f; unsigned int i; } v; v.f = f;
  unsigned int r = v.i + 0x7fffu + ((v.i >> 16) & 1u); // RNE
  return (unsigned short)(r >> 16);
}
__device__ __forceinline__ float bf2f(unsigned short u) {
  union { unsigned int i; float f; } v; v.i = ((unsigned int)u) << 16; return v.f;
}

// async global->LDS, 16B per lane. LDS dest = wave-uniform base + lane*16 (m104).
__device__ __forceinline__ void gload_lds16(const unsigned short* g, unsigned short* l) {
  __builtin_amdgcn_global_load_lds(
      (const __attribute__((address_space(1))) unsigned int*)g,
      (__attribute__((address_space(3))) unsigned int*)(unsigned int)(size_t)l,
      16, 0, 0);
}

// ---- weight convert+transpose+swizzle ----
// w1T/w2T: logical (d,c) d=0..127 out-col, c=0..127 k. 16B chunk (c>>3) stored at
// chunk^(d&15). rw1T/rw2T: (k,d,c) 64x64; chunk (c>>3) stored at chunk^(d&7)
// (swizzle baked into global layout so linear gload_lds staging lands swizzled).
__global__ __launch_bounds__(256) void k_prep(
    const float* __restrict__ w1, const float* __restrict__ w2,
    const float* __restrict__ rw1, const float* __restrict__ rw2,
    unsigned short* __restrict__ w1T, unsigned short* __restrict__ w2T,
    unsigned short* __restrict__ rw1T, unsigned short* __restrict__ rw2T) {
  int t = blockIdx.x * 256 + threadIdx.x;
  if (t < 128 * 128) {
    int c = t >> 7, d = t & 127;
    int pos = d * 128 + ((((c >> 3) ^ (d & 15)) << 3) | (c & 7));
    w1T[pos] = f2bf(w1[t]);
    w2T[pos] = f2bf(w2[t]);
  }
  if (t < 27 * 64 * 64) {
    int k = t >> 12, r = t & 4095, c = r >> 6, d = r & 63;
    int pos = (k << 12) + d * 64 + ((((c >> 3) ^ (d & 7)) << 3) | (c & 7));
    rw1T[pos] = f2bf(rw1[t]);
    rw2T[pos] = f2bf(rw2[t]);
  }
}

// ---- y = bf16(x) @ w1 + b1 ; w1T staged in LDS once; 16 rows/wave ----
__global__ __launch_bounds__(256) void k_gemm_in(
    const float* __restrict__ x, const unsigned short* __restrict__ w1T,
    const float* __restrict__ b1, unsigned short* __restrict__ y) {
  __shared__ unsigned short sw[16384]; // 32KB
  const int tid = threadIdx.x, lane = tid & 63, w = tid >> 6;
  const int m16 = lane & 15, q = lane >> 4;
#pragma unroll
  for (int r = 0; r < 8; ++r) {
    const int off = (w * 8 + r) * 512 + lane * 8;
    gload_lds16(w1T + off, &sw[off]);
  }
  __syncthreads();
  const int rowbase = blockIdx.x * 64 + w * 16;
  const int r0 = rowbase + m16;
  const int rc = r0 < N_PTS ? r0 : N_PTS - 1;
  f32x4 acc[8] = {};
#pragma unroll
  for (int kk = 0; kk < 4; ++kk) {
    const float* xp = x + (size_t)rc * 128 + kk * 32 + q * 8;
    float4 f0 = *(const float4*)xp;
    float4 f1 = *(const float4*)(xp + 4);
    frag_ab a;
    a[0] = (short)f2bf(f0.x); a[1] = (short)f2bf(f0.y);
    a[2] = (short)f2bf(f0.z); a[3] = (short)f2bf(f0.w);
    a[4] = (short)f2bf(f1.x); a[5] = (short)f2bf(f1.y);
    a[6] = (short)f2bf(f1.z); a[7] = (short)f2bf(f1.w);
#pragma unroll
    for (int ct = 0; ct < 8; ++ct) {
      const int d = ct * 16 + m16;
      const int phys = ((kk << 2) | q) ^ m16;
      frag_ab bf = *(const frag_ab*)(&sw[d * 128 + phys * 8]);
      acc[ct] = __builtin_amdgcn_mfma_f32_16x16x32_bf16(a, bf, acc[ct], 0, 0, 0);
    }
  }
#pragma unroll
  for (int ct = 0; ct < 8; ++ct) {
    const int col = ct * 16 + m16;
    const float bias = b1[col];
#pragma unroll
    for (int j = 0; j < 4; ++j) {
      int r = rowbase + q * 4 + j;
      if (r < N_PTS) y[(size_t)r * 128 + col] = f2bf(acc[ct][j] + bias);
    }
  }
}

// ---- gathered sparse conv: counted-vmcnt pipeline, raw barriers ----
// 128 rows/block (4 waves x 32 rows). Main loop k=0..23, per iter exactly 8
// vmem issues, all unique valid addresses:
//   stage weights k+2 (2 global_load_lds) -> LDS ring slot (k+2)&3
//   nbr prefetch k+3 (2 loads)
//   A-gather k+1 (4 loads, clamped row index; zero-select at consume)
// then s_waitcnt vmcnt(8) (everything >=1 iter old retired), sched_barrier(0),
// ds_read B + 16 MFMA, raw s_barrier. Epilogue k=24/25/26 issues 6/4/0 ops with
// exact waits vmcnt(6)/(4)/(0). No duplicate addresses anywhere -> no CSE ->
// counts exact. All ring indices compile-time (outer loop k0 % 4 == 0).
template <bool FUSE>
__global__ __launch_bounds__(256) void k_conv(
    const unsigned short* __restrict__ feat, const int fstride,
    const int* __restrict__ nbr,
    const unsigned short* __restrict__ rwT, const float* __restrict__ rb,
    const unsigned short* __restrict__ res, unsigned short* __restrict__ out) {
  __shared__ unsigned short sw[4][4096]; // 4-deep ring, 8 KB per k-slice
  const int tid = threadIdx.x, lane = tid & 63, w = tid >> 6;
  const int m16 = lane & 15, q = lane >> 4;
  const int rowbase = blockIdx.x * 128 + w * 32;
  const int p0 = rowbase + m16, p1 = p0 + 16;
  const bool v0 = p0 < N_PTS, v1 = p1 < N_PTS;
  const int pc0 = v0 ? p0 : N_PTS - 1, pc1 = v1 ? p1 : N_PTS - 1;
  const int s0 = w * 1024 + lane * 8; // ushort idx of this thread's 16B chunk
  const int s1 = s0 + 512;

  int I[4][2];        // raw nbr ring (validity select deferred to use)
  int im[2][2];       // masked index for the A slot (consume-time zero test)
  frag_ab A[2][2][2]; // [slot][rt][kk]
  f32x4 acc[2][4] = {};

#define CONV_GATHER(slot, isrc)                                                 \
  {                                                                             \
    const int i0 = v0 ? (isrc)[0] : -1;                                         \
    const int i1 = v1 ? (isrc)[1] : -1;                                         \
    im[slot][0] = i0; im[slot][1] = i1;                                         \
    const size_t j0 = (size_t)(i0 < 0 ? 0 : i0);                                \
    const size_t j1 = (size_t)(i1 < 0 ? 0 : i1);                                \
    const unsigned short* f0 = feat + j0 * fstride + q * 8;                     \
    const unsigned short* f1 = feat + j1 * fstride + q * 8;                     \
    A[slot][0][0] = *(const frag_ab*)f0; A[slot][0][1] = *(const frag_ab*)(f0 + 32); \
    A[slot][1][0] = *(const frag_ab*)f1; A[slot][1][1] = *(const frag_ab*)(f1 + 32); \
  }

#define CONV_COMPUTE(buf, slot)                                                 \
  {                                                                             \
    frag_ab Ac[2][2];                                                           \
    _Pragma("unroll") for (int rt = 0; rt < 2; ++rt)                            \
      _Pragma("unroll") for (int kk = 0; kk < 2; ++kk) {                        \
        frag_ab a = A[slot][rt][kk];                                            \
        if (im[slot][rt] < 0) a = ZFRAG;                                        \
        Ac[rt][kk] = a;                                                         \
      }                                                                         \
    _Pragma("unroll") for (int kk = 0; kk < 2; ++kk)                            \
      _Pragma("unroll") for (int ct = 0; ct < 4; ++ct) {                        \
        const int d = ct * 16 + m16;                                            \
        const int phys = ((kk << 2) | q) ^ (m16 & 7);                           \
        frag_ab bf = *(const frag_ab*)(&sw[buf][d * 64 + phys * 8]);            \
        acc[0][ct] = __builtin_amdgcn_mfma_f32_16x16x32_bf16(Ac[0][kk], bf, acc[0][ct], 0, 0, 0); \
        acc[1][ct] = __builtin_amdgcn_mfma_f32_16x16x32_bf16(Ac[1][kk], bf, acc[1][ct], 0, 0, 0); \
      }                                                                         \
  }

  // ---- prologue: stage k=0,1; load I[0..2] (kc=0,1,2); gather A slot0 (k=0) ----
  gload_lds16(rwT + s0, &sw[0][s0]);
  gload_lds16(rwT + s1, &sw[0][s1]);
  gload_lds16(rwT + 4096 + s0, &sw[1][s0]);
  gload_lds16(rwT + 4096 + s1, &sw[1][s1]);
#pragma unroll
  for (int s = 0; s < 3; ++s) {
    I[s][0] = nbr[(size_t)s * N_PTS + pc0];
    I[s][1] = nbr[(size_t)s * N_PTS + pc1];
  }
  CONV_GATHER(0, I[0]);
  __builtin_amdgcn_s_barrier();

  // ---- main loop: k = 0..23 (outer runtime, inner unrolled; k0 % 4 == 0) ----
  for (int k0 = 0; k0 < 24; k0 += 4) {
#pragma unroll
    for (int u = 0; u < 4; ++u) {
      const int k = k0 + u;
      const int cur = u & 1, nxt = cur ^ 1;
      // 1) stage weights k+2 (<= 25, always valid, unique) -> slot (u+2)&3
      {
        const unsigned short* src = rwT + ((size_t)(k + 2) << 12);
        unsigned short* dst = sw[(u + 2) & 3];
        gload_lds16(src + s0, dst + s0);
        gload_lds16(src + s1, dst + s1);
      }
      // 2) nbr prefetch k+3 (<= 26, always valid, unique) -> I[(u+3)&3]
      I[(u + 3) & 3][0] = nbr[(size_t)(k + 3) * N_PTS + pc0];
      I[(u + 3) & 3][1] = nbr[(size_t)(k + 3) * N_PTS + pc1];
      // 3) A-gather for k+1 using I[(u+1)&3]
      CONV_GATHER(nxt, I[(u + 1) & 3]);
      // 4) counted wait: exactly this iter's 8 ops left in flight
      asm volatile("s_waitcnt vmcnt(8)" ::: "memory");
      __builtin_amdgcn_sched_barrier(0);
      // 5+6) compute k from slot u&3
      CONV_COMPUTE(u & 3, cur);
      __builtin_amdgcn_s_barrier();
    }
  }

  // ---- epilogue: k = 24, 25, 26 with exact counts ----
  { // k = 24 (cur slot 0): stage ks=26 -> slot 2; gather k=25 via I[1]
    const unsigned short* src = rwT + ((size_t)26 << 12);
    gload_lds16(src + s0, &sw[2][s0]);
    gload_lds16(src + s1, &sw[2][s1]);
    CONV_GATHER(1, I[1]);
    asm volatile("s_waitcnt vmcnt(6)" ::: "memory");
    __builtin_amdgcn_sched_barrier(0);
    CONV_COMPUTE(0, 0);
    __builtin_amdgcn_s_barrier();
  }
  { // k = 25 (cur slot 1): gather k=26 via I[2]
    CONV_GATHER(0, I[2]);
    asm volatile("s_waitcnt vmcnt(4)" ::: "memory");
    __builtin_amdgcn_sched_barrier(0);
    CONV_COMPUTE(1, 1);
    __builtin_amdgcn_s_barrier();
  }
  { // k = 26 (cur slot 0): no loads
    asm volatile("s_waitcnt vmcnt(0)" ::: "memory");
    __builtin_amdgcn_sched_barrier(0);
    CONV_COMPUTE(2, 0);
  }
#undef CONV_GATHER
#undef CONV_COMPUTE

#pragma unroll
  for (int ct = 0; ct < 4; ++ct) {
    const int col = ct * 16 + m16;
    const float bias = rb[col];
#pragma unroll
    for (int rt = 0; rt < 2; ++rt)
#pragma unroll
      for (int j = 0; j < 4; ++j) {
        const int r = rowbase + rt * 16 + q * 4 + j;
        if (r < N_PTS) {
          float v = acc[rt][ct][j] + bias;
          v = v > 0.f ? v : 0.f;
          if constexpr (FUSE) v += 2.f * bf2f(res[(size_t)r * 128 + col]);
          out[(size_t)r * 64 + col] = f2bf(v);
        }
      }
  }
}

// ---- out = x + [z1 | y[:,64:]] @ w2 + b2 ; w2T staged in LDS once; 16 rows/wave ----
__global__ __launch_bounds__(256) void k_gemm_out(
    const float* __restrict__ x, const unsigned short* __restrict__ z1,
    const unsigned short* __restrict__ y, const unsigned short* __restrict__ w2T,
    const float* __restrict__ b2, float* __restrict__ out) {
  __shared__ unsigned short sw[16384]; // 32KB
  const int tid = threadIdx.x, lane = tid & 63, w = tid >> 6;
  const int m16 = lane & 15, q = lane >> 4;
#pragma unroll
  for (int r = 0; r < 8; ++r) {
    const int off = (w * 8 + r) * 512 + lane * 8;
    gload_lds16(w2T + off, &sw[off]);
  }
  __syncthreads();
  const int rowbase = blockIdx.x * 64 + w * 16;
  const int r0 = rowbase + m16;
  const int rc = r0 < N_PTS ? r0 : N_PTS - 1;
  f32x4 acc[8] = {};
#pragma unroll
  for (int kk = 0; kk < 4; ++kk) {
    const unsigned short* ap = (kk < 2)
        ? (z1 + (size_t)rc * 64 + kk * 32 + q * 8)
        : (y + (size_t)rc * 128 + 64 + (kk - 2) * 32 + q * 8);
    frag_ab a = *(const frag_ab*)ap;
#pragma unroll
    for (int ct = 0; ct < 8; ++ct) {
      const int d = ct * 16 + m16;
      const int phys = ((kk << 2) | q) ^ m16;
      frag_ab bf = *(const frag_ab*)(&sw[d * 128 + phys * 8]);
      acc[ct] = __builtin_amdgcn_mfma_f32_16x16x32_bf16(a, bf, acc[ct], 0, 0, 0);
    }
  }
#pragma unroll
  for (int ct = 0; ct < 8; ++ct) {
    const int col = ct * 16 + m16;
    const float bias = b2[col];
#pragma unroll
    for (int j = 0; j < 4; ++j) {
      int r = rowbase + q * 4 + j;
      if (r < N_PTS) {
        size_t o = (size_t)r * 128 + col;
        out[o] = acc[ct][j] + bias + x[o];
      }
    }
  }
}

extern "C" void kernel_launch(void* const* d_in, const int* in_sizes, int n_in,
                              void* d_out, int out_size, void* d_ws, size_t ws_size,
                              hipStream_t stream) {
  const float* x   = (const float*)d_in[0];
  const float* w1  = (const float*)d_in[1];
  const float* b1  = (const float*)d_in[2];
  const float* w2  = (const float*)d_in[3];
  const float* b2  = (const float*)d_in[4];
  const float* rw1 = (const float*)d_in[5];
  const float* rb1 = (const float*)d_in[6];
  const float* rw2 = (const float*)d_in[7];
  const float* rb2 = (const float*)d_in[8];
  const int* nbr = (const int*)d_in[9];
  float* out = (float*)d_out;

  char* ws = (char*)d_ws;
  unsigned short* w1T  = (unsigned short*)(ws);                       // 32 KB
  unsigned short* w2T  = (unsigned short*)(ws + 32768);               // 32 KB
  unsigned short* rw1T = (unsigned short*)(ws + 65536);               // 216 KB
  unsigned short* rw2T = (unsigned short*)(ws + 286720);              // 216 KB
  unsigned short* y    = (unsigned short*)(ws + 507904);              // 25.6 MB
  unsigned short* r1   = (unsigned short*)(ws + 507904 + 25600000);   // 12.8 MB
  unsigned short* z1   = (unsigned short*)(ws + 507904 + 38400000);   // 12.8 MB

  k_prep<<<432, 256, 0, stream>>>(w1, w2, rw1, rw2, w1T, w2T, rw1T, rw2T);
  k_gemm_in<<<NBLK64, 256, 0, stream>>>(x, w1T, b1, y);
  k_conv<false><<<NBLK128, 256, 0, stream>>>(y, 128, nbr, rw1T, rb1, nullptr, r1);
  k_conv<true><<<NBLK128, 256, 0, stream>>>(r1, 64, nbr, rw2T, rb2, y, z1);
  k_gemm_out<<<NBLK64, 256, 0, stream>>>(x, z1, y, w2T, b2, out);
}